// Round 24
// baseline (179.128 us; speedup 1.0000x reference)
//
#include <hip/hip_runtime.h>
#include <hip/hip_bf16.h>
#include <cstdint>
#include <cstddef>

typedef __bf16 bf16x8 __attribute__((ext_vector_type(8)));
typedef float  f32x4  __attribute__((ext_vector_type(4)));
typedef unsigned short u16x8 __attribute__((ext_vector_type(8)));

#define S_TOT 1024
#define NH 12
#define HD 64
#define NBH 48
#define CDIM 768
#define L2E 1.44269504088896f

static __device__ __forceinline__ unsigned short f2bf(float f) {
    unsigned int u = __builtin_bit_cast(unsigned int, f);
    u += 0x7FFFu + ((u >> 16) & 1u);
    return (unsigned short)(u >> 16);
}

// raw v_exp_f32 (hardware exp2) — avoids libm fixup code
static __device__ __forceinline__ float exp2_raw(float x) {
    float r;
    asm("v_exp_f32 %0, %1" : "=v"(r) : "v"(x));
    return r;
}

// tanh-approx GELU: x * sigmoid(1.5957691*(x + 0.044715 x^3)); sigmoid via exp2
static __device__ __forceinline__ float gelu_fast(float x) {
    float u = x * (1.0f + 0.044715f * x * x);
    float e = exp2_raw(-2.3022090f * u);
    return x / (1.0f + e);
}

// async global->LDS 16B DMA (wave-uniform LDS base + lane*16 ordering required)
static __device__ __forceinline__ void async16(void* lds, const void* g) {
    __builtin_amdgcn_global_load_lds(
        (const __attribute__((address_space(1))) unsigned int*)g,
        (__attribute__((address_space(3))) unsigned int*)lds, 16, 0, 0);
}

// A-panel-resident XCD partition (requires gridDim.x == 64).
static __device__ __forceinline__ void xcd_part(int orig, int& bm_idx, int& bn_idx) {
    bm_idx = ((orig & 7) << 3) + ((orig >> 3) & 7);
    bn_idx = orig >> 6;
}

// ---------------- Fused: weight transpose (blocks 0..6911) + LayerNorm1 (blocks 6912..11007) ----------------
__launch_bounds__(256)
__global__ void wtln_kernel(const float* __restrict__ qkv_w, const float* __restrict__ proj_w,
                            const float* __restrict__ w1, const float* __restrict__ w2,
                            unsigned short* __restrict__ wTq, unsigned short* __restrict__ wTp,
                            unsigned short* __restrict__ wT1, unsigned short* __restrict__ wT2,
                            const float* __restrict__ x, const float* __restrict__ lnw,
                            const float* __restrict__ lnb, unsigned short* __restrict__ lnout)
{
    __shared__ float tile[32][33];
    const int tid = threadIdx.x;
    if (blockIdx.x >= 6912) {
        const int row = blockIdx.x - 6912;
        const float* xr = x + (size_t)row * CDIM;
        float v0 = xr[tid], v1 = xr[tid + 256], v2 = xr[tid + 512];
        float s  = v0 + v1 + v2;
        float s2 = v0 * v0 + v1 * v1 + v2 * v2;
        #pragma unroll
        for (int off = 32; off > 0; off >>= 1) {
            s  += __shfl_xor(s,  off);
            s2 += __shfl_xor(s2, off);
        }
        __shared__ float ss[4], ss2[4];
        const int wid = tid >> 6;
        if ((tid & 63) == 0) { ss[wid] = s; ss2[wid] = s2; }
        __syncthreads();
        s  = ss[0] + ss[1] + ss[2] + ss[3];
        s2 = ss2[0] + ss2[1] + ss2[2] + ss2[3];
        const float mu  = s * (1.0f / CDIM);
        const float var = s2 * (1.0f / CDIM) - mu * mu;
        const float rs  = rsqrtf(var + 1e-5f);
        unsigned short* orow = lnout + (size_t)row * CDIM;
        float vv[3] = {v0, v1, v2};
        #pragma unroll
        for (int i = 0; i < 3; ++i) {
            int c = tid + i * 256;
            orow[c] = f2bf((vv[i] - mu) * rs * lnw[c] + lnb[c]);
        }
        return;
    }
    int id = blockIdx.x;
    const float* W; unsigned short* WT; int K, N, ko, no;
    if (id < 1728)      { W = qkv_w;  WT = wTq; K = 768;  N = 2304;            ko = id % 24; no = id / 24; }
    else if (id < 2304) { W = proj_w; WT = wTp; K = 768;  N = 768;  id -= 1728; ko = id % 24; no = id / 24; }
    else if (id < 4608) { W = w1;     WT = wT1; K = 768;  N = 3072; id -= 2304; ko = id % 24; no = id / 24; }
    else                { W = w2;     WT = wT2; K = 3072; N = 768;  id -= 4608; ko = id % 96; no = id / 96; }
    const int k0 = ko * 32, n0 = no * 32;
    const int tx = tid & 31, ty = tid >> 5;
    #pragma unroll
    for (int i = 0; i < 4; ++i) {
        int kk = ty + i * 8;
        tile[kk][tx] = W[(size_t)(k0 + kk) * N + n0 + tx];
    }
    __syncthreads();
    #pragma unroll
    for (int i = 0; i < 4; ++i) {
        int nn = ty + i * 8;
        WT[(size_t)(n0 + nn) * K + k0 + tx] = f2bf(tile[tx][nn]);
    }
}

// ---------------- LayerNorm (standalone, for ln2): [rows][768] f32 -> bf16 ----------------
__launch_bounds__(256)
__global__ void ln_kernel(const float* __restrict__ x, const float* __restrict__ w,
                          const float* __restrict__ b, unsigned short* __restrict__ out)
{
    const int row = blockIdx.x;
    const int tid = threadIdx.x;
    const float* xr = x + (size_t)row * CDIM;
    float v0 = xr[tid], v1 = xr[tid + 256], v2 = xr[tid + 512];
    float s  = v0 + v1 + v2;
    float s2 = v0 * v0 + v1 * v1 + v2 * v2;
    #pragma unroll
    for (int off = 32; off > 0; off >>= 1) {
        s  += __shfl_xor(s,  off);
        s2 += __shfl_xor(s2, off);
    }
    __shared__ float ss[4], ss2[4];
    const int wid = tid >> 6;
    if ((tid & 63) == 0) { ss[wid] = s; ss2[wid] = s2; }
    __syncthreads();
    s  = ss[0] + ss[1] + ss[2] + ss[3];
    s2 = ss2[0] + ss2[1] + ss2[2] + ss2[3];
    const float mu  = s * (1.0f / CDIM);
    const float var = s2 * (1.0f / CDIM) - mu * mu;
    const float rs  = rsqrtf(var + 1e-5f);
    unsigned short* orow = out + (size_t)row * CDIM;
    float vv[3] = {v0, v1, v2};
    #pragma unroll
    for (int i = 0; i < 3; ++i) {
        int c = tid + i * 256;
        orow[c] = f2bf((vv[i] - mu) * rs * w[c] + b[c]);
    }
}

// ------------- V transpose: v[bh][s][d] bf16 -> vT[bh][d][s] bf16 -------------
__launch_bounds__(256)
__global__ void vtrans_kernel(const unsigned short* __restrict__ v,
                              unsigned short* __restrict__ vT)
{
    __shared__ unsigned short tile[64][65];
    const int bh = blockIdx.x;
    const int s0 = blockIdx.y * 64;
    const int tid = threadIdx.x;
    #pragma unroll
    for (int it = 0; it < 2; ++it) {
        int idx = tid + it * 256;
        int r = idx >> 3, c0 = (idx & 7) * 8;
        *(u16x8*)&tile[r][c0] = *(const u16x8*)&v[((size_t)bh * S_TOT + s0 + r) * HD + c0];
    }
    __syncthreads();
    #pragma unroll
    for (int it = 0; it < 2; ++it) {
        int idx = tid + it * 256;
        int d = idx >> 3, sc = (idx & 7) * 8;
        u16x8 o;
        #pragma unroll
        for (int e = 0; e < 8; ++e) o[e] = tile[sc + e][d];
        *(u16x8*)&vT[((size_t)bh * HD + d) * S_TOT + s0 + sc] = o;
    }
}

// ---------------- GEMM 64x256, BK=64 (single-buffer, 40 KB; 4 waves x 64x64): C = A*BT + epi ----------------
// Per-wave 64x64 tile: 8 ds_read_b128 per ks for 16 MFMA = 0.5 reads/MFMA (LDS-BW fix).
// EPI 0: QKV scatter (+bias) -> bf16; EPI 2: +bias GELU -> bf16.
template<int EPI>
__launch_bounds__(256)
__global__ void gemm64x256_kernel(const unsigned short* __restrict__ A,
                                  const unsigned short* __restrict__ BT,
                                  const float* __restrict__ bias,
                                  unsigned short* __restrict__ outh,
                                  int M, int N, int K)
{
    __shared__ __align__(16) unsigned short As[64 * 64];
    __shared__ __align__(16) unsigned short Bs[256 * 64];
    const int tid  = threadIdx.x;
    int bmi, bni;
    xcd_part(blockIdx.y * gridDim.x + blockIdx.x, bmi, bni);
    const int bm   = bmi * 64;
    const int bn   = bni * 256;
    const int wid  = tid >> 6, lane = tid & 63;
    const int wc   = wid * 64;
    const int fr   = lane & 15, fk = lane >> 4;

    f32x4 acc[4][4] = {};

    for (int kk = 0; kk < K; kk += 64) {
        __syncthreads();
        #pragma unroll
        for (int it = 0; it < 8; ++it) {
            int idx = tid + it * 256;
            int r = idx >> 3;
            int j = (idx & 7) ^ (r & 7);
            async16(&Bs[idx * 8], &BT[(size_t)(bn + r) * K + kk + j * 8]);
            if (it < 2)
                async16(&As[idx * 8], &A[(size_t)(bm + r) * K + kk + j * 8]);
        }
        __syncthreads();
        #pragma unroll
        for (int ks = 0; ks < 2; ++ks) {
            bf16x8 af[4], bfv[4];
            #pragma unroll
            for (int i = 0; i < 4; ++i) {
                int Ra = i * 16 + fr;
                af[i] = *(const bf16x8*)&As[Ra * 64 + (((ks * 4 + fk) ^ (Ra & 7)) * 8)];
            }
            #pragma unroll
            for (int j = 0; j < 4; ++j) {
                int Rb = wc + j * 16 + fr;
                bfv[j] = *(const bf16x8*)&Bs[Rb * 64 + (((ks * 4 + fk) ^ (Rb & 7)) * 8)];
            }
            __builtin_amdgcn_s_setprio(1);
            #pragma unroll
            for (int i = 0; i < 4; ++i)
                #pragma unroll
                for (int j = 0; j < 4; ++j)
                    acc[i][j] = __builtin_amdgcn_mfma_f32_16x16x32_bf16(af[i], bfv[j], acc[i][j], 0, 0, 0);
            __builtin_amdgcn_s_setprio(0);
        }
    }

    const int er = (lane >> 4) * 4;
    const int ec = lane & 15;
    #pragma unroll
    for (int i = 0; i < 4; ++i) {
        const int rowb = bm + i * 16 + er;
        #pragma unroll
        for (int j = 0; j < 4; ++j) {
            const int col = bn + wc + j * 16 + ec;
            #pragma unroll
            for (int r = 0; r < 4; ++r) {
                const int row = rowb + r;
                float val = acc[i][j][r] + bias[col];
                if constexpr (EPI == 0) {
                    int bb = row >> 10, s = row & 1023;
                    int t  = col / CDIM;
                    int rem = col - t * CDIM;
                    int hh = rem >> 6, d = rem & 63;
                    outh[((size_t)(t * NBH + bb * NH + hh) * S_TOT + s) * HD + d] = f2bf(val);
                } else {
                    outh[(size_t)row * N + col] = f2bf(gelu_fast(val));
                }
            }
        }
    }
}

// ---------------- GEMM 64x64, BK=128 (single-buffer, 32 KB): + bias + res -> f32 ----------------
__launch_bounds__(256)
__global__ void gemm64_kernel(const unsigned short* __restrict__ A,
                              const unsigned short* __restrict__ BT,
                              const float* __restrict__ bias,
                              const float* __restrict__ res,
                              float* __restrict__ outf,
                              int M, int N, int K)
{
    __shared__ __align__(16) unsigned short As[64 * 128];
    __shared__ __align__(16) unsigned short Bs[64 * 128];
    const int tid  = threadIdx.x;
    int bmi, bni;
    xcd_part(blockIdx.y * gridDim.x + blockIdx.x, bmi, bni);
    const int bm   = bmi * 64;
    const int bn   = bni * 64;
    const int wid  = tid >> 6, lane = tid & 63;
    const int wr   = (wid >> 1) * 32, wc = (wid & 1) * 32;
    const int fr   = lane & 15, fk = lane >> 4;

    f32x4 acc[2][2] = {};

    for (int kk = 0; kk < K; kk += 128) {
        __syncthreads();
        #pragma unroll
        for (int it = 0; it < 4; ++it) {
            int idx = tid + it * 256;
            int r = idx >> 4;
            int jj = (idx & 15) ^ (r & 7);
            async16(&As[idx * 8], &A[(size_t)(bm + r) * K + kk + jj * 8]);
            async16(&Bs[idx * 8], &BT[(size_t)(bn + r) * K + kk + jj * 8]);
        }
        __syncthreads();
        #pragma unroll
        for (int ks = 0; ks < 4; ++ks) {
            bf16x8 af[2], bfv[2];
            #pragma unroll
            for (int i = 0; i < 2; ++i) {
                int Ra = wr + i * 16 + fr;
                af[i]  = *(const bf16x8*)&As[Ra * 128 + (((ks * 4 + fk) ^ (Ra & 7)) * 8)];
                int Rb = wc + i * 16 + fr;
                bfv[i] = *(const bf16x8*)&Bs[Rb * 128 + (((ks * 4 + fk) ^ (Rb & 7)) * 8)];
            }
            __builtin_amdgcn_s_setprio(1);
            #pragma unroll
            for (int i = 0; i < 2; ++i)
                #pragma unroll
                for (int j = 0; j < 2; ++j)
                    acc[i][j] = __builtin_amdgcn_mfma_f32_16x16x32_bf16(af[i], bfv[j], acc[i][j], 0, 0, 0);
            __builtin_amdgcn_s_setprio(0);
        }
    }

    const int er = (lane >> 4) * 4;
    const int ec = lane & 15;
    #pragma unroll
    for (int i = 0; i < 2; ++i) {
        const int rowb = bm + wr + i * 16 + er;
        #pragma unroll
        for (int j = 0; j < 2; ++j) {
            const int col = bn + wc + j * 16 + ec;
            #pragma unroll
            for (int r = 0; r < 4; ++r) {
                const int row = rowb + r;
                size_t idx = (size_t)row * N + col;
                outf[idx] = acc[i][j][r] + bias[col] + res[idx];
            }
        }
    }
}

// ---------------- Rel-pos bias tables via MFMA (output scaled by log2(e)) ----------------
__launch_bounds__(256)
__global__ void bias_kernel(const unsigned short* __restrict__ q,
                            const float* __restrict__ rel_h,
                            const float* __restrict__ rel_w,
                            float* __restrict__ biasH,
                            float* __restrict__ biasW)
{
    __shared__ __align__(16) unsigned short Bl[32 * 72];
    const int tid  = threadIdx.x;
    const int wid  = tid >> 6, lane = tid & 63;
    const int fr   = lane & 15, fk = lane >> 4;
    const int mt   = blockIdx.x;
    const int qc   = blockIdx.y;
    const int mode = blockIdx.z;
    const float* rel = mode ? rel_w : rel_h;
    float* outp = mode ? biasW : biasH;

    {
        int row = tid >> 3, c0 = (tid & 7) * 8;
        const float* rp = rel + (size_t)(qc + 31 - row) * HD + c0;
        u16x8 o;
        #pragma unroll
        for (int e = 0; e < 8; ++e) o[e] = f2bf(rp[e]);
        *(u16x8*)&Bl[row * 72 + c0] = o;
    }
    __syncthreads();

    const int ri = wid * 16 + fr;
    const int bh = mt * 2 + (ri >> 5);
    const int inner = ri & 31;
    const int s = mode ? (inner * 32 + qc) : (qc * 32 + inner);
    const unsigned short* arow = q + ((size_t)bh * S_TOT + s) * HD;

    f32x4 acc[2] = {};
    #pragma unroll
    for (int ks = 0; ks < 2; ++ks) {
        bf16x8 af = *(const bf16x8*)&arow[ks * 32 + fk * 8];
        #pragma unroll
        for (int nt = 0; nt < 2; ++nt) {
            bf16x8 bfv = *(const bf16x8*)&Bl[(nt * 16 + fr) * 72 + ks * 32 + fk * 8];
            acc[nt] = __builtin_amdgcn_mfma_f32_16x16x32_bf16(af, bfv, acc[nt], 0, 0, 0);
        }
    }

    const int g = lane >> 4, c = lane & 15;
    #pragma unroll
    for (int reg = 0; reg < 4; ++reg) {
        int ro = wid * 16 + g * 4 + reg;
        int bho = mt * 2 + (ro >> 5);
        int io  = ro & 31;
        int so  = mode ? (io * 32 + qc) : (qc * 32 + io);
        float* op = outp + ((size_t)bho * S_TOT + so) * 32;
        op[c]      = acc[0][reg] * L2E;
        op[16 + c] = acc[1][reg] * L2E;
    }
}

// ---------------- MFMA flash attention: QBLK=64, KVBLK=128 ----------------
__launch_bounds__(256, 3)
__global__ void attn_kernel(const unsigned short* __restrict__ qkv,
                            const unsigned short* __restrict__ vT,
                            const float* __restrict__ biasH,
                            const float* __restrict__ biasW,
                            unsigned short* __restrict__ out)
{
    __shared__ __align__(16) unsigned short Ks[128 * 64];
    __shared__ __align__(16) unsigned short Vt[64 * 128];
    __shared__ __align__(16) unsigned short Pst[4][16][136];

    const int tid  = threadIdx.x;
    const int wid  = tid >> 6;
    const int lane = tid & 63;
    const int fr   = lane & 15, fk = lane >> 4;
    const int er   = (lane >> 4) * 4, ec = lane & 15;
    const int bh_  = blockIdx.x % NBH;
    const int qt   = blockIdx.x / NBH;
    const int row0 = qt * 64;
    const int b    = bh_ / NH, h = bh_ - b * NH;

    const unsigned short* q = qkv;
    const unsigned short* k = qkv + (size_t)NBH * S_TOT * HD;
    const size_t headoff  = (size_t)bh_ * S_TOT * HD;
    const size_t vheadoff = (size_t)bh_ * HD * S_TOT;

    #pragma unroll
    for (int it = 0; it < 2; ++it) {
        int idx = tid + it * 256;
        int r = idx >> 3;
        int j = (idx & 7) ^ (r & 7);
        async16(&Ks[idx * 8], &q[headoff + (size_t)(row0 + r) * HD + j * 8]);
    }
    __syncthreads();

    bf16x8 qf[2];
    {
        int Rq = wid * 16 + fr;
        qf[0] = *(const bf16x8*)&Ks[Rq * 64 + ((fk ^ (Rq & 7)) * 8)];
        qf[1] = *(const bf16x8*)&Ks[Rq * 64 + (((4 + fk) ^ (Rq & 7)) * 8)];
    }

    float bh0[4], bh1[4], bw0[4], bw1[4];
    {
        const int g = lane >> 4, c = lane & 15;
        #pragma unroll
        for (int reg = 0; reg < 4; ++reg) {
            int rt = row0 + wid * 16 + g * 4 + reg;
            const float* ph = biasH + ((size_t)bh_ * S_TOT + rt) * 32;
            const float* pw = biasW + ((size_t)bh_ * S_TOT + rt) * 32;
            bh0[reg] = ph[c];  bh1[reg] = ph[16 + c];
            bw0[reg] = pw[c];  bw1[reg] = pw[16 + c];
        }
    }

    const u16x8 ones_u = {0x3F80, 0x3F80, 0x3F80, 0x3F80, 0x3F80, 0x3F80, 0x3F80, 0x3F80};
    const bf16x8 ones = __builtin_bit_cast(bf16x8, ones_u);
    const float SCL = 0.125f * L2E;

    float m[4], l[4];
    f32x4 oacc[4];
    #pragma unroll
    for (int r = 0; r < 4; ++r) {
        m[r] = -1e30f; l[r] = 0.f;
        oacc[r][0] = 0.f; oacc[r][1] = 0.f; oacc[r][2] = 0.f; oacc[r][3] = 0.f;
    }

    for (int KT = 0; KT < 8; ++KT) {
        __syncthreads();
        #pragma unroll
        for (int it = 0; it < 4; ++it) {
            int idx = tid + it * 256;
            int r = idx >> 3;
            int j = (idx & 7) ^ (r & 7);
            async16(&Ks[idx * 8], &k[headoff + (size_t)(KT * 128 + r) * HD + j * 8]);
        }
        #pragma unroll
        for (int it = 0; it < 4; ++it) {
            int idx = tid + it * 256;
            int r = idx >> 4;
            int j = (idx & 15) ^ (r & 7);
            async16(&Vt[idx * 8], &vT[vheadoff + (size_t)r * S_TOT + KT * 128 + j * 8]);
        }
        __syncthreads();

        f32x4 sacc[8];
        #pragma unroll
        for (int nt = 0; nt < 8; ++nt) {
            sacc[nt][0] = 0.f; sacc[nt][1] = 0.f; sacc[nt][2] = 0.f; sacc[nt][3] = 0.f;
        }
        __builtin_amdgcn_s_setprio(1);
        #pragma unroll
        for (int nt = 0; nt < 8; ++nt) {
            int Rk = nt * 16 + fr;
            bf16x8 b0 = *(const bf16x8*)&Ks[Rk * 64 + ((fk ^ (Rk & 7)) * 8)];
            bf16x8 b1 = *(const bf16x8*)&Ks[Rk * 64 + (((4 + fk) ^ (Rk & 7)) * 8)];
            sacc[nt] = __builtin_amdgcn_mfma_f32_16x16x32_bf16(qf[0], b0, sacc[nt], 0, 0, 0);
            sacc[nt] = __builtin_amdgcn_mfma_f32_16x16x32_bf16(qf[1], b1, sacc[nt], 0, 0, 0);
        }
        __builtin_amdgcn_s_setprio(0);

        float bhv[4][4];
        #pragma unroll
        for (int jj = 0; jj < 4; ++jj) {
            int kh = KT * 4 + jj;
            int src = ((lane >> 4) << 4) + (kh & 15);
            #pragma unroll
            for (int reg = 0; reg < 4; ++reg)
                bhv[jj][reg] = (kh < 16) ? __shfl(bh0[reg], src) : __shfl(bh1[reg], src);
        }

        float tmax[4] = {-1e30f, -1e30f, -1e30f, -1e30f};
        #pragma unroll
        for (int nt = 0; nt < 8; ++nt) {
            #pragma unroll
            for (int reg = 0; reg < 4; ++reg) {
                float s_ = sacc[nt][reg] * SCL + bhv[nt >> 1][reg]
                         + ((nt & 1) ? bw1[reg] : bw0[reg]);
                sacc[nt][reg] = s_;
                tmax[reg] = fmaxf(tmax[reg], s_);
            }
        }
        #pragma unroll
        for (int reg = 0; reg < 4; ++reg) {
            #pragma unroll
            for (int off = 8; off > 0; off >>= 1)
                tmax[reg] = fmaxf(tmax[reg], __shfl_xor(tmax[reg], off));
            float mnew = fmaxf(m[reg], tmax[reg]);
            float c = exp2_raw(m[reg] - mnew);
            m[reg] = mnew;
            #pragma unroll
            for (int nt = 0; nt < 8; ++nt) {
                float p = exp2_raw(sacc[nt][reg] - mnew);
                Pst[wid][er + reg][nt * 16 + ec] = f2bf(p);
            }
            l[reg] *= c;
            #pragma unroll
            for (int nt = 0; nt < 4; ++nt) oacc[nt][reg] *= c;
        }

        __builtin_amdgcn_s_setprio(1);
        bf16x8 pa[4];
        #pragma unroll
        for (int ks = 0; ks < 4; ++ks)
            pa[ks] = *(const bf16x8*)&Pst[wid][fr][ks * 32 + fk * 8];
        f32x4 ps = {};
        #pragma unroll
        for (int ks = 0; ks < 4; ++ks)
            ps = __builtin_amdgcn_mfma_f32_16x16x32_bf16(pa[ks], ones, ps, 0, 0, 0);
        #pragma unroll
        for (int nt = 0; nt < 4; ++nt) {
            int Rv = nt * 16 + fr;
            #pragma unroll
            for (int ks = 0; ks < 4; ++ks) {
                int ch = (ks * 4 + fk) ^ (Rv & 7);
                bf16x8 vb = *(const bf16x8*)&Vt[Rv * 128 + ch * 8];
                oacc[nt] = __builtin_amdgcn_mfma_f32_16x16x32_bf16(pa[ks], vb, oacc[nt], 0, 0, 0);
            }
        }
        __builtin_amdgcn_s_setprio(0);
        #pragma unroll
        for (int reg = 0; reg < 4; ++reg) l[reg] += ps[reg];
    }

    #pragma unroll
    for (int reg = 0; reg < 4; ++reg) {
        float inv = 1.0f / l[reg];
        int srow = row0 + wid * 16 + er + reg;
        #pragma unroll
        for (int nt = 0; nt < 4; ++nt) {
            out[((size_t)(b * S_TOT + srow)) * CDIM + h * HD + nt * 16 + ec] =
                f2bf(oacc[nt][reg] * inv);
        }
    }
}

extern "C" void kernel_launch(void* const* d_in, const int* in_sizes, int n_in,
                              void* d_out, int out_size, void* d_ws, size_t ws_size,
                              hipStream_t stream)
{
    const float* x      = (const float*)d_in[0];
    const float* n1w    = (const float*)d_in[1];
    const float* n1b    = (const float*)d_in[2];
    const float* qkv_w  = (const float*)d_in[3];
    const float* qkv_b  = (const float*)d_in[4];
    const float* proj_w = (const float*)d_in[5];
    const float* proj_b = (const float*)d_in[6];
    const float* rel_h  = (const float*)d_in[7];
    const float* rel_w  = (const float*)d_in[8];
    const float* n2w    = (const float*)d_in[9];
    const float* n2b    = (const float*)d_in[10];
    const float* w1     = (const float*)d_in[11];
    const float* b1     = (const float*)d_in[12];
    const float* w2     = (const float*)d_in[13];
    const float* b2     = (const float*)d_in[14];

    char* ws = (char*)d_ws;
    unsigned short* qkvbf = (unsigned short*)(ws + 0);
    float*          biasH = (float*)(ws + 18874368);
    float*          biasW = (float*)(ws + 25165824);
    unsigned short* hbf   = (unsigned short*)(ws + 0);
    float*          x1    = (float*)(ws + 25165824);
    unsigned short* xnbf  = (unsigned short*)(ws + 37748736);
    unsigned short* vTbuf = (unsigned short*)(ws + 37748736);   // aliases xnbf (dead region)
    unsigned short* wTq   = (unsigned short*)(ws + 44040192);
    unsigned short* wTp   = (unsigned short*)(ws + 47579136);
    unsigned short* wT1   = (unsigned short*)(ws + 48758784);
    unsigned short* wT2   = (unsigned short*)(ws + 53477376);
    unsigned short* aout  = (unsigned short*)(ws + 58195968);

    // fused weight-transpose + LN1 (independent work, runs concurrently)
    wtln_kernel<<<11008, 256, 0, stream>>>(qkv_w, proj_w, w1, w2, wTq, wTp, wT1, wT2,
                                           x, n1w, n1b, xnbf);
    gemm64x256_kernel<0><<<dim3(64, 9), 256, 0, stream>>>(xnbf, wTq, qkv_b, qkvbf, 4096, 2304, 768);
    vtrans_kernel<<<dim3(48, 16), 256, 0, stream>>>(qkvbf + (size_t)2 * NBH * S_TOT * HD, vTbuf);
    bias_kernel<<<dim3(24, 32, 2), 256, 0, stream>>>(qkvbf, rel_h, rel_w, biasH, biasW);
    attn_kernel<<<768, 256, 0, stream>>>(qkvbf, vTbuf, biasH, biasW, aout);
    gemm64_kernel<<<dim3(64, 12), 256, 0, stream>>>(aout, wTp, proj_b, x, x1, 4096, 768, 768);
    ln_kernel<<<4096, 256, 0, stream>>>(x1, n2w, n2b, xnbf);
    gemm64x256_kernel<2><<<dim3(64, 12), 256, 0, stream>>>(xnbf, wT1, b1, hbf, 4096, 3072, 768);
    gemm64_kernel<<<dim3(64, 12), 256, 0, stream>>>(hbf, wT2, b2, x1, (float*)d_out, 4096, 768, 3072);
}

// Round 25
// 161.591 us; speedup vs baseline: 1.1085x; 1.1085x over previous
//
#include <hip/hip_runtime.h>
#include <hip/hip_bf16.h>
#include <cstdint>
#include <cstddef>

typedef __bf16 bf16x8 __attribute__((ext_vector_type(8)));
typedef float  f32x4  __attribute__((ext_vector_type(4)));
typedef unsigned short u16x8 __attribute__((ext_vector_type(8)));

#define S_TOT 1024
#define NH 12
#define HD 64
#define NBH 48
#define CDIM 768
#define L2E 1.44269504088896f

static __device__ __forceinline__ unsigned short f2bf(float f) {
    unsigned int u = __builtin_bit_cast(unsigned int, f);
    u += 0x7FFFu + ((u >> 16) & 1u);
    return (unsigned short)(u >> 16);
}

// raw v_exp_f32 (hardware exp2) — avoids libm fixup code
static __device__ __forceinline__ float exp2_raw(float x) {
    float r;
    asm("v_exp_f32 %0, %1" : "=v"(r) : "v"(x));
    return r;
}

// tanh-approx GELU: x * sigmoid(1.5957691*(x + 0.044715 x^3)); sigmoid via exp2
static __device__ __forceinline__ float gelu_fast(float x) {
    float u = x * (1.0f + 0.044715f * x * x);
    float e = exp2_raw(-2.3022090f * u);
    return x / (1.0f + e);
}

// async global->LDS 16B DMA (wave-uniform LDS base + lane*16 ordering required)
static __device__ __forceinline__ void async16(void* lds, const void* g) {
    __builtin_amdgcn_global_load_lds(
        (const __attribute__((address_space(1))) unsigned int*)g,
        (__attribute__((address_space(3))) unsigned int*)lds, 16, 0, 0);
}

// A-panel-resident XCD partition (requires gridDim.x == 64).
static __device__ __forceinline__ void xcd_part(int orig, int& bm_idx, int& bn_idx) {
    bm_idx = ((orig & 7) << 3) + ((orig >> 3) & 7);
    bn_idx = orig >> 6;
}

// ---------------- Fused: weight transpose (blocks 0..6911) + LayerNorm1 (blocks 6912..11007) ----------------
__launch_bounds__(256)
__global__ void wtln_kernel(const float* __restrict__ qkv_w, const float* __restrict__ proj_w,
                            const float* __restrict__ w1, const float* __restrict__ w2,
                            unsigned short* __restrict__ wTq, unsigned short* __restrict__ wTp,
                            unsigned short* __restrict__ wT1, unsigned short* __restrict__ wT2,
                            const float* __restrict__ x, const float* __restrict__ lnw,
                            const float* __restrict__ lnb, unsigned short* __restrict__ lnout)
{
    __shared__ float tile[32][33];
    const int tid = threadIdx.x;
    if (blockIdx.x >= 6912) {
        const int row = blockIdx.x - 6912;
        const float* xr = x + (size_t)row * CDIM;
        float v0 = xr[tid], v1 = xr[tid + 256], v2 = xr[tid + 512];
        float s  = v0 + v1 + v2;
        float s2 = v0 * v0 + v1 * v1 + v2 * v2;
        #pragma unroll
        for (int off = 32; off > 0; off >>= 1) {
            s  += __shfl_xor(s,  off);
            s2 += __shfl_xor(s2, off);
        }
        __shared__ float ss[4], ss2[4];
        const int wid = tid >> 6;
        if ((tid & 63) == 0) { ss[wid] = s; ss2[wid] = s2; }
        __syncthreads();
        s  = ss[0] + ss[1] + ss[2] + ss[3];
        s2 = ss2[0] + ss2[1] + ss2[2] + ss2[3];
        const float mu  = s * (1.0f / CDIM);
        const float var = s2 * (1.0f / CDIM) - mu * mu;
        const float rs  = rsqrtf(var + 1e-5f);
        unsigned short* orow = lnout + (size_t)row * CDIM;
        float vv[3] = {v0, v1, v2};
        #pragma unroll
        for (int i = 0; i < 3; ++i) {
            int c = tid + i * 256;
            orow[c] = f2bf((vv[i] - mu) * rs * lnw[c] + lnb[c]);
        }
        return;
    }
    int id = blockIdx.x;
    const float* W; unsigned short* WT; int K, N, ko, no;
    if (id < 1728)      { W = qkv_w;  WT = wTq; K = 768;  N = 2304;            ko = id % 24; no = id / 24; }
    else if (id < 2304) { W = proj_w; WT = wTp; K = 768;  N = 768;  id -= 1728; ko = id % 24; no = id / 24; }
    else if (id < 4608) { W = w1;     WT = wT1; K = 768;  N = 3072; id -= 2304; ko = id % 24; no = id / 24; }
    else                { W = w2;     WT = wT2; K = 3072; N = 768;  id -= 4608; ko = id % 96; no = id / 96; }
    const int k0 = ko * 32, n0 = no * 32;
    const int tx = tid & 31, ty = tid >> 5;
    #pragma unroll
    for (int i = 0; i < 4; ++i) {
        int kk = ty + i * 8;
        tile[kk][tx] = W[(size_t)(k0 + kk) * N + n0 + tx];
    }
    __syncthreads();
    #pragma unroll
    for (int i = 0; i < 4; ++i) {
        int nn = ty + i * 8;
        WT[(size_t)(n0 + nn) * K + k0 + tx] = f2bf(tile[tx][nn]);
    }
}

// ---------------- LayerNorm (standalone, for ln2): [rows][768] f32 -> bf16 ----------------
__launch_bounds__(256)
__global__ void ln_kernel(const float* __restrict__ x, const float* __restrict__ w,
                          const float* __restrict__ b, unsigned short* __restrict__ out)
{
    const int row = blockIdx.x;
    const int tid = threadIdx.x;
    const float* xr = x + (size_t)row * CDIM;
    float v0 = xr[tid], v1 = xr[tid + 256], v2 = xr[tid + 512];
    float s  = v0 + v1 + v2;
    float s2 = v0 * v0 + v1 * v1 + v2 * v2;
    #pragma unroll
    for (int off = 32; off > 0; off >>= 1) {
        s  += __shfl_xor(s,  off);
        s2 += __shfl_xor(s2, off);
    }
    __shared__ float ss[4], ss2[4];
    const int wid = tid >> 6;
    if ((tid & 63) == 0) { ss[wid] = s; ss2[wid] = s2; }
    __syncthreads();
    s  = ss[0] + ss[1] + ss[2] + ss[3];
    s2 = ss2[0] + ss2[1] + ss2[2] + ss2[3];
    const float mu  = s * (1.0f / CDIM);
    const float var = s2 * (1.0f / CDIM) - mu * mu;
    const float rs  = rsqrtf(var + 1e-5f);
    unsigned short* orow = out + (size_t)row * CDIM;
    float vv[3] = {v0, v1, v2};
    #pragma unroll
    for (int i = 0; i < 3; ++i) {
        int c = tid + i * 256;
        orow[c] = f2bf((vv[i] - mu) * rs * w[c] + b[c]);
    }
}

// ------------- V transpose: v[bh][s][d] bf16 -> vT[bh][d][s] bf16 -------------
__launch_bounds__(256)
__global__ void vtrans_kernel(const unsigned short* __restrict__ v,
                              unsigned short* __restrict__ vT)
{
    __shared__ unsigned short tile[64][65];
    const int bh = blockIdx.x;
    const int s0 = blockIdx.y * 64;
    const int tid = threadIdx.x;
    #pragma unroll
    for (int it = 0; it < 2; ++it) {
        int idx = tid + it * 256;
        int r = idx >> 3, c0 = (idx & 7) * 8;
        *(u16x8*)&tile[r][c0] = *(const u16x8*)&v[((size_t)bh * S_TOT + s0 + r) * HD + c0];
    }
    __syncthreads();
    #pragma unroll
    for (int it = 0; it < 2; ++it) {
        int idx = tid + it * 256;
        int d = idx >> 3, sc = (idx & 7) * 8;
        u16x8 o;
        #pragma unroll
        for (int e = 0; e < 8; ++e) o[e] = tile[sc + e][d];
        *(u16x8*)&vT[((size_t)bh * HD + d) * S_TOT + s0 + sc] = o;
    }
}

// ---------------- GEMM 64x128, BK=128 (single-buffer, 48 KB): C = A * BT + epilogue ----------------
template<int EPI>
__launch_bounds__(256)
__global__ void gemm64x128_kernel(const unsigned short* __restrict__ A,
                                  const unsigned short* __restrict__ BT,
                                  const float* __restrict__ bias,
                                  unsigned short* __restrict__ outh,
                                  int M, int N, int K)
{
    __shared__ __align__(16) unsigned short As[64 * 128];
    __shared__ __align__(16) unsigned short Bs[128 * 128];
    const int tid  = threadIdx.x;
    int bmi, bni;
    xcd_part(blockIdx.y * gridDim.x + blockIdx.x, bmi, bni);
    const int bm   = bmi * 64;
    const int bn   = bni * 128;
    const int wid  = tid >> 6, lane = tid & 63;
    const int wr   = (wid >> 1) * 32, wc = (wid & 1) * 64;
    const int fr   = lane & 15, fk = lane >> 4;

    f32x4 acc[2][4] = {};

    for (int kk = 0; kk < K; kk += 128) {
        __syncthreads();
        #pragma unroll
        for (int it = 0; it < 8; ++it) {
            int idx = tid + it * 256;
            int r = idx >> 4;
            int jj = (idx & 15) ^ (r & 7);
            async16(&Bs[idx * 8], &BT[(size_t)(bn + r) * K + kk + jj * 8]);
            if (it < 4)
                async16(&As[idx * 8], &A[(size_t)(bm + r) * K + kk + jj * 8]);
        }
        __syncthreads();
        #pragma unroll
        for (int ks = 0; ks < 4; ++ks) {
            bf16x8 af[2], bfv[4];
            #pragma unroll
            for (int i = 0; i < 2; ++i) {
                int Ra = wr + i * 16 + fr;
                af[i] = *(const bf16x8*)&As[Ra * 128 + (((ks * 4 + fk) ^ (Ra & 7)) * 8)];
            }
            #pragma unroll
            for (int j = 0; j < 4; ++j) {
                int Rb = wc + j * 16 + fr;
                bfv[j] = *(const bf16x8*)&Bs[Rb * 128 + (((ks * 4 + fk) ^ (Rb & 7)) * 8)];
            }
            __builtin_amdgcn_s_setprio(1);
            #pragma unroll
            for (int i = 0; i < 2; ++i)
                #pragma unroll
                for (int j = 0; j < 4; ++j)
                    acc[i][j] = __builtin_amdgcn_mfma_f32_16x16x32_bf16(af[i], bfv[j], acc[i][j], 0, 0, 0);
            __builtin_amdgcn_s_setprio(0);
        }
    }

    const int er = (lane >> 4) * 4;
    const int ec = lane & 15;
    #pragma unroll
    for (int i = 0; i < 2; ++i) {
        const int rowb = bm + wr + i * 16 + er;
        #pragma unroll
        for (int j = 0; j < 4; ++j) {
            const int col = bn + wc + j * 16 + ec;
            #pragma unroll
            for (int r = 0; r < 4; ++r) {
                const int row = rowb + r;
                float val = acc[i][j][r] + bias[col];
                if constexpr (EPI == 0) {
                    int bb = row >> 10, s = row & 1023;
                    int t  = col / CDIM;
                    int rem = col - t * CDIM;
                    int hh = rem >> 6, d = rem & 63;
                    outh[((size_t)(t * NBH + bb * NH + hh) * S_TOT + s) * HD + d] = f2bf(val);
                } else {
                    outh[(size_t)row * N + col] = f2bf(gelu_fast(val));
                }
            }
        }
    }
}

// ---------------- GEMM 64x64, BK=128 (single-buffer, 32 KB): + bias + res -> f32 ----------------
__launch_bounds__(256)
__global__ void gemm64_kernel(const unsigned short* __restrict__ A,
                              const unsigned short* __restrict__ BT,
                              const float* __restrict__ bias,
                              const float* __restrict__ res,
                              float* __restrict__ outf,
                              int M, int N, int K)
{
    __shared__ __align__(16) unsigned short As[64 * 128];
    __shared__ __align__(16) unsigned short Bs[64 * 128];
    const int tid  = threadIdx.x;
    int bmi, bni;
    xcd_part(blockIdx.y * gridDim.x + blockIdx.x, bmi, bni);
    const int bm   = bmi * 64;
    const int bn   = bni * 64;
    const int wid  = tid >> 6, lane = tid & 63;
    const int wr   = (wid >> 1) * 32, wc = (wid & 1) * 32;
    const int fr   = lane & 15, fk = lane >> 4;

    f32x4 acc[2][2] = {};

    for (int kk = 0; kk < K; kk += 128) {
        __syncthreads();
        #pragma unroll
        for (int it = 0; it < 4; ++it) {
            int idx = tid + it * 256;
            int r = idx >> 4;
            int jj = (idx & 15) ^ (r & 7);
            async16(&As[idx * 8], &A[(size_t)(bm + r) * K + kk + jj * 8]);
            async16(&Bs[idx * 8], &BT[(size_t)(bn + r) * K + kk + jj * 8]);
        }
        __syncthreads();
        #pragma unroll
        for (int ks = 0; ks < 4; ++ks) {
            bf16x8 af[2], bfv[2];
            #pragma unroll
            for (int i = 0; i < 2; ++i) {
                int Ra = wr + i * 16 + fr;
                af[i]  = *(const bf16x8*)&As[Ra * 128 + (((ks * 4 + fk) ^ (Ra & 7)) * 8)];
                int Rb = wc + i * 16 + fr;
                bfv[i] = *(const bf16x8*)&Bs[Rb * 128 + (((ks * 4 + fk) ^ (Rb & 7)) * 8)];
            }
            __builtin_amdgcn_s_setprio(1);
            #pragma unroll
            for (int i = 0; i < 2; ++i)
                #pragma unroll
                for (int j = 0; j < 2; ++j)
                    acc[i][j] = __builtin_amdgcn_mfma_f32_16x16x32_bf16(af[i], bfv[j], acc[i][j], 0, 0, 0);
            __builtin_amdgcn_s_setprio(0);
        }
    }

    const int er = (lane >> 4) * 4;
    const int ec = lane & 15;
    #pragma unroll
    for (int i = 0; i < 2; ++i) {
        const int rowb = bm + wr + i * 16 + er;
        #pragma unroll
        for (int j = 0; j < 2; ++j) {
            const int col = bn + wc + j * 16 + ec;
            #pragma unroll
            for (int r = 0; r < 4; ++r) {
                const int row = rowb + r;
                size_t idx = (size_t)row * N + col;
                outf[idx] = acc[i][j][r] + bias[col] + res[idx];
            }
        }
    }
}

// ---------------- Rel-pos bias tables via MFMA (output scaled by log2(e)) ----------------
__launch_bounds__(256)
__global__ void bias_kernel(const unsigned short* __restrict__ q,
                            const float* __restrict__ rel_h,
                            const float* __restrict__ rel_w,
                            float* __restrict__ biasH,
                            float* __restrict__ biasW)
{
    __shared__ __align__(16) unsigned short Bl[32 * 72];
    const int tid  = threadIdx.x;
    const int wid  = tid >> 6, lane = tid & 63;
    const int fr   = lane & 15, fk = lane >> 4;
    const int mt   = blockIdx.x;
    const int qc   = blockIdx.y;
    const int mode = blockIdx.z;
    const float* rel = mode ? rel_w : rel_h;
    float* outp = mode ? biasW : biasH;

    {
        int row = tid >> 3, c0 = (tid & 7) * 8;
        const float* rp = rel + (size_t)(qc + 31 - row) * HD + c0;
        u16x8 o;
        #pragma unroll
        for (int e = 0; e < 8; ++e) o[e] = f2bf(rp[e]);
        *(u16x8*)&Bl[row * 72 + c0] = o;
    }
    __syncthreads();

    const int ri = wid * 16 + fr;
    const int bh = mt * 2 + (ri >> 5);
    const int inner = ri & 31;
    const int s = mode ? (inner * 32 + qc) : (qc * 32 + inner);
    const unsigned short* arow = q + ((size_t)bh * S_TOT + s) * HD;

    f32x4 acc[2] = {};
    #pragma unroll
    for (int ks = 0; ks < 2; ++ks) {
        bf16x8 af = *(const bf16x8*)&arow[ks * 32 + fk * 8];
        #pragma unroll
        for (int nt = 0; nt < 2; ++nt) {
            bf16x8 bfv = *(const bf16x8*)&Bl[(nt * 16 + fr) * 72 + ks * 32 + fk * 8];
            acc[nt] = __builtin_amdgcn_mfma_f32_16x16x32_bf16(af, bfv, acc[nt], 0, 0, 0);
        }
    }

    const int g = lane >> 4, c = lane & 15;
    #pragma unroll
    for (int reg = 0; reg < 4; ++reg) {
        int ro = wid * 16 + g * 4 + reg;
        int bho = mt * 2 + (ro >> 5);
        int io  = ro & 31;
        int so  = mode ? (io * 32 + qc) : (qc * 32 + io);
        float* op = outp + ((size_t)bho * S_TOT + so) * 32;
        op[c]      = acc[0][reg] * L2E;
        op[16 + c] = acc[1][reg] * L2E;
    }
}

// ---------------- MFMA flash attention: QBLK=64, KVBLK=128 ----------------
__launch_bounds__(256, 3)
__global__ void attn_kernel(const unsigned short* __restrict__ qkv,
                            const unsigned short* __restrict__ vT,
                            const float* __restrict__ biasH,
                            const float* __restrict__ biasW,
                            unsigned short* __restrict__ out)
{
    __shared__ __align__(16) unsigned short Ks[128 * 64];
    __shared__ __align__(16) unsigned short Vt[64 * 128];
    __shared__ __align__(16) unsigned short Pst[4][16][136];

    const int tid  = threadIdx.x;
    const int wid  = tid >> 6;
    const int lane = tid & 63;
    const int fr   = lane & 15, fk = lane >> 4;
    const int er   = (lane >> 4) * 4, ec = lane & 15;
    const int bh_  = blockIdx.x % NBH;
    const int qt   = blockIdx.x / NBH;
    const int row0 = qt * 64;
    const int b    = bh_ / NH, h = bh_ - b * NH;

    const unsigned short* q = qkv;
    const unsigned short* k = qkv + (size_t)NBH * S_TOT * HD;
    const size_t headoff  = (size_t)bh_ * S_TOT * HD;
    const size_t vheadoff = (size_t)bh_ * HD * S_TOT;

    #pragma unroll
    for (int it = 0; it < 2; ++it) {
        int idx = tid + it * 256;
        int r = idx >> 3;
        int j = (idx & 7) ^ (r & 7);
        async16(&Ks[idx * 8], &q[headoff + (size_t)(row0 + r) * HD + j * 8]);
    }
    __syncthreads();

    bf16x8 qf[2];
    {
        int Rq = wid * 16 + fr;
        qf[0] = *(const bf16x8*)&Ks[Rq * 64 + ((fk ^ (Rq & 7)) * 8)];
        qf[1] = *(const bf16x8*)&Ks[Rq * 64 + (((4 + fk) ^ (Rq & 7)) * 8)];
    }

    float bh0[4], bh1[4], bw0[4], bw1[4];
    {
        const int g = lane >> 4, c = lane & 15;
        #pragma unroll
        for (int reg = 0; reg < 4; ++reg) {
            int rt = row0 + wid * 16 + g * 4 + reg;
            const float* ph = biasH + ((size_t)bh_ * S_TOT + rt) * 32;
            const float* pw = biasW + ((size_t)bh_ * S_TOT + rt) * 32;
            bh0[reg] = ph[c];  bh1[reg] = ph[16 + c];
            bw0[reg] = pw[c];  bw1[reg] = pw[16 + c];
        }
    }

    const u16x8 ones_u = {0x3F80, 0x3F80, 0x3F80, 0x3F80, 0x3F80, 0x3F80, 0x3F80, 0x3F80};
    const bf16x8 ones = __builtin_bit_cast(bf16x8, ones_u);
    const float SCL = 0.125f * L2E;

    float m[4], l[4];
    f32x4 oacc[4];
    #pragma unroll
    for (int r = 0; r < 4; ++r) {
        m[r] = -1e30f; l[r] = 0.f;
        oacc[r][0] = 0.f; oacc[r][1] = 0.f; oacc[r][2] = 0.f; oacc[r][3] = 0.f;
    }

    for (int KT = 0; KT < 8; ++KT) {
        __syncthreads();
        #pragma unroll
        for (int it = 0; it < 4; ++it) {
            int idx = tid + it * 256;
            int r = idx >> 3;
            int j = (idx & 7) ^ (r & 7);
            async16(&Ks[idx * 8], &k[headoff + (size_t)(KT * 128 + r) * HD + j * 8]);
        }
        #pragma unroll
        for (int it = 0; it < 4; ++it) {
            int idx = tid + it * 256;
            int r = idx >> 4;
            int j = (idx & 15) ^ (r & 7);
            async16(&Vt[idx * 8], &vT[vheadoff + (size_t)r * S_TOT + KT * 128 + j * 8]);
        }
        __syncthreads();

        f32x4 sacc[8];
        #pragma unroll
        for (int nt = 0; nt < 8; ++nt) {
            sacc[nt][0] = 0.f; sacc[nt][1] = 0.f; sacc[nt][2] = 0.f; sacc[nt][3] = 0.f;
        }
        __builtin_amdgcn_s_setprio(1);
        #pragma unroll
        for (int nt = 0; nt < 8; ++nt) {
            int Rk = nt * 16 + fr;
            bf16x8 b0 = *(const bf16x8*)&Ks[Rk * 64 + ((fk ^ (Rk & 7)) * 8)];
            bf16x8 b1 = *(const bf16x8*)&Ks[Rk * 64 + (((4 + fk) ^ (Rk & 7)) * 8)];
            sacc[nt] = __builtin_amdgcn_mfma_f32_16x16x32_bf16(qf[0], b0, sacc[nt], 0, 0, 0);
            sacc[nt] = __builtin_amdgcn_mfma_f32_16x16x32_bf16(qf[1], b1, sacc[nt], 0, 0, 0);
        }
        __builtin_amdgcn_s_setprio(0);

        float bhv[4][4];
        #pragma unroll
        for (int jj = 0; jj < 4; ++jj) {
            int kh = KT * 4 + jj;
            int src = ((lane >> 4) << 4) + (kh & 15);
            #pragma unroll
            for (int reg = 0; reg < 4; ++reg)
                bhv[jj][reg] = (kh < 16) ? __shfl(bh0[reg], src) : __shfl(bh1[reg], src);
        }

        float tmax[4] = {-1e30f, -1e30f, -1e30f, -1e30f};
        #pragma unroll
        for (int nt = 0; nt < 8; ++nt) {
            #pragma unroll
            for (int reg = 0; reg < 4; ++reg) {
                float s_ = sacc[nt][reg] * SCL + bhv[nt >> 1][reg]
                         + ((nt & 1) ? bw1[reg] : bw0[reg]);
                sacc[nt][reg] = s_;
                tmax[reg] = fmaxf(tmax[reg], s_);
            }
        }
        #pragma unroll
        for (int reg = 0; reg < 4; ++reg) {
            #pragma unroll
            for (int off = 8; off > 0; off >>= 1)
                tmax[reg] = fmaxf(tmax[reg], __shfl_xor(tmax[reg], off));
            float mnew = fmaxf(m[reg], tmax[reg]);
            float c = exp2_raw(m[reg] - mnew);
            m[reg] = mnew;
            #pragma unroll
            for (int nt = 0; nt < 8; ++nt) {
                float p = exp2_raw(sacc[nt][reg] - mnew);
                Pst[wid][er + reg][nt * 16 + ec] = f2bf(p);
            }
            l[reg] *= c;
            #pragma unroll
            for (int nt = 0; nt < 4; ++nt) oacc[nt][reg] *= c;
        }

        __builtin_amdgcn_s_setprio(1);
        bf16x8 pa[4];
        #pragma unroll
        for (int ks = 0; ks < 4; ++ks)
            pa[ks] = *(const bf16x8*)&Pst[wid][fr][ks * 32 + fk * 8];
        f32x4 ps = {};
        #pragma unroll
        for (int ks = 0; ks < 4; ++ks)
            ps = __builtin_amdgcn_mfma_f32_16x16x32_bf16(pa[ks], ones, ps, 0, 0, 0);
        #pragma unroll
        for (int nt = 0; nt < 4; ++nt) {
            int Rv = nt * 16 + fr;
            #pragma unroll
            for (int ks = 0; ks < 4; ++ks) {
                int ch = (ks * 4 + fk) ^ (Rv & 7);
                bf16x8 vb = *(const bf16x8*)&Vt[Rv * 128 + ch * 8];
                oacc[nt] = __builtin_amdgcn_mfma_f32_16x16x32_bf16(pa[ks], vb, oacc[nt], 0, 0, 0);
            }
        }
        __builtin_amdgcn_s_setprio(0);
        #pragma unroll
        for (int reg = 0; reg < 4; ++reg) l[reg] += ps[reg];
    }

    #pragma unroll
    for (int reg = 0; reg < 4; ++reg) {
        float inv = 1.0f / l[reg];
        int srow = row0 + wid * 16 + er + reg;
        #pragma unroll
        for (int nt = 0; nt < 4; ++nt) {
            out[((size_t)(b * S_TOT + srow)) * CDIM + h * HD + nt * 16 + ec] =
                f2bf(oacc[nt][reg] * inv);
        }
    }
}

extern "C" void kernel_launch(void* const* d_in, const int* in_sizes, int n_in,
                              void* d_out, int out_size, void* d_ws, size_t ws_size,
                              hipStream_t stream)
{
    const float* x      = (const float*)d_in[0];
    const float* n1w    = (const float*)d_in[1];
    const float* n1b    = (const float*)d_in[2];
    const float* qkv_w  = (const float*)d_in[3];
    const float* qkv_b  = (const float*)d_in[4];
    const float* proj_w = (const float*)d_in[5];
    const float* proj_b = (const float*)d_in[6];
    const float* rel_h  = (const float*)d_in[7];
    const float* rel_w  = (const float*)d_in[8];
    const float* n2w    = (const float*)d_in[9];
    const float* n2b    = (const float*)d_in[10];
    const float* w1     = (const float*)d_in[11];
    const float* b1     = (const float*)d_in[12];
    const float* w2     = (const float*)d_in[13];
    const float* b2     = (const float*)d_in[14];

    char* ws = (char*)d_ws;
    unsigned short* qkvbf = (unsigned short*)(ws + 0);
    float*          biasH = (float*)(ws + 18874368);
    float*          biasW = (float*)(ws + 25165824);
    unsigned short* hbf   = (unsigned short*)(ws + 0);
    float*          x1    = (float*)(ws + 25165824);
    unsigned short* xnbf  = (unsigned short*)(ws + 37748736);
    unsigned short* vTbuf = (unsigned short*)(ws + 37748736);   // aliases xnbf (dead region)
    unsigned short* wTq   = (unsigned short*)(ws + 44040192);
    unsigned short* wTp   = (unsigned short*)(ws + 47579136);
    unsigned short* wT1   = (unsigned short*)(ws + 48758784);
    unsigned short* wT2   = (unsigned short*)(ws + 53477376);
    unsigned short* aout  = (unsigned short*)(ws + 58195968);

    // fused weight-transpose + LN1 (independent work, runs concurrently)
    wtln_kernel<<<11008, 256, 0, stream>>>(qkv_w, proj_w, w1, w2, wTq, wTp, wT1, wT2,
                                           x, n1w, n1b, xnbf);
    gemm64x128_kernel<0><<<dim3(64, 18), 256, 0, stream>>>(xnbf, wTq, qkv_b, qkvbf, 4096, 2304, 768);
    vtrans_kernel<<<dim3(48, 16), 256, 0, stream>>>(qkvbf + (size_t)2 * NBH * S_TOT * HD, vTbuf);
    bias_kernel<<<dim3(24, 32, 2), 256, 0, stream>>>(qkvbf, rel_h, rel_w, biasH, biasW);
    attn_kernel<<<768, 256, 0, stream>>>(qkvbf, vTbuf, biasH, biasW, aout);
    gemm64_kernel<<<dim3(64, 12), 256, 0, stream>>>(aout, wTp, proj_b, x, x1, 4096, 768, 768);
    ln_kernel<<<4096, 256, 0, stream>>>(x1, n2w, n2b, xnbf);
    gemm64x128_kernel<2><<<dim3(64, 24), 256, 0, stream>>>(xnbf, wT1, b1, hbf, 4096, 3072, 768);
    gemm64_kernel<<<dim3(64, 12), 256, 0, stream>>>(hbf, wT2, b2, x1, (float*)d_out, 4096, 768, 3072);
}